// Round 1
// baseline (837.315 us; speedup 1.0000x reference)
//
#include <hip/hip_runtime.h>

#define KC 24
#define DC 128
#define TPB 256
#define ROWS_PER_BLOCK 512
#define NROWS 524288

// workspace accumulator layout (floats):
// [0, KC*DC)          embedding sums
// [KC*DC, KC*DC+KC)   cluster counts
// [KC*DC+KC]          loss sum
#define ACC_FLOATS (KC * DC + KC + 1)

__global__ void vq_zero_acc(float* __restrict__ acc) {
    int i = blockIdx.x * blockDim.x + threadIdx.x;
    if (i < ACC_FLOATS) acc[i] = 0.0f;
}

__global__ __launch_bounds__(TPB) void vq_main(
    const float* __restrict__ z_e, const float* __restrict__ cb,
    float* __restrict__ o_soft, float* __restrict__ o_hard,
    float* __restrict__ o_idx, float* __restrict__ o_w,
    float* __restrict__ acc)
{
    __shared__ float cb_s[KC][DC + 4];   // +4 pad: breaks bank aliasing for per-idx reads/atomics
    __shared__ float wn_s[KC];
    __shared__ float ebin[KC][DC + 4];
    __shared__ float cnt_s[KC];
    __shared__ float loss_s;

    const int tid = threadIdx.x;

    #pragma unroll 1
    for (int i = tid; i < KC * DC; i += TPB) cb_s[i >> 7][i & (DC - 1)] = cb[i];
    #pragma unroll 1
    for (int i = tid; i < KC * (DC + 4); i += TPB) (&ebin[0][0])[i] = 0.0f;
    if (tid < KC) cnt_s[tid] = 0.0f;
    if (tid == 0) loss_s = 0.0f;
    __syncthreads();
    if (tid < KC) {
        float s = 0.0f;
        #pragma unroll 1
        for (int d = 0; d < DC; ++d) s = fmaf(cb_s[tid][d], cb_s[tid][d], s);
        wn_s[tid] = s;
    }
    __syncthreads();

    const int r0 = blockIdx.x * ROWS_PER_BLOCK + tid;
    const int r1 = r0 + TPB;
    const float* zp0 = z_e + (size_t)r0 * DC;
    const float* zp1 = z_e + (size_t)r1 * DC;

    float dot0[KC], dot1[KC];
    #pragma unroll
    for (int k = 0; k < KC; ++k) { dot0[k] = 0.0f; dot1[k] = 0.0f; }
    float zn0 = 0.0f, zn1 = 0.0f;

    // ---- Pass A: dot products + ||z||^2 ----
    #pragma unroll 1
    for (int c = 0; c < DC / 4; ++c) {
        const float4 a = *(const float4*)(zp0 + 4 * c);
        const float4 b = *(const float4*)(zp1 + 4 * c);
        zn0 = fmaf(a.x, a.x, fmaf(a.y, a.y, fmaf(a.z, a.z, fmaf(a.w, a.w, zn0))));
        zn1 = fmaf(b.x, b.x, fmaf(b.y, b.y, fmaf(b.z, b.z, fmaf(b.w, b.w, zn1))));
        #pragma unroll
        for (int k = 0; k < KC; ++k) {
            const float4 w = *(const float4*)(&cb_s[k][4 * c]);   // uniform -> LDS broadcast
            dot0[k] = fmaf(a.x, w.x, fmaf(a.y, w.y, fmaf(a.z, w.z, fmaf(a.w, w.w, dot0[k]))));
            dot1[k] = fmaf(b.x, w.x, fmaf(b.y, w.y, fmaf(b.z, w.z, fmaf(b.w, w.w, dot1[k]))));
        }
    }

    // ---- dists, argmin (first-min), softmax ----
    int idx0 = 0, idx1 = 0;
    float best0 = 3.4e38f, best1 = 3.4e38f;
    #pragma unroll
    for (int k = 0; k < KC; ++k) {
        const float wn = wn_s[k];
        float d0 = (zn0 - 2.0f * dot0[k]) + wn;   // reference formula order
        float d1 = (zn1 - 2.0f * dot1[k]) + wn;
        dot0[k] = d0; dot1[k] = d1;               // reuse as dist storage
        if (d0 < best0) { best0 = d0; idx0 = k; }
        if (d1 < best1) { best1 = d1; idx1 = k; }
    }
    float s0 = 0.0f, s1 = 0.0f;
    #pragma unroll
    for (int k = 0; k < KC; ++k) {
        float e0 = __expf(best0 - dot0[k]);   // logit - max  (shift-exact)
        float e1 = __expf(best1 - dot1[k]);
        dot0[k] = e0; dot1[k] = e1;
        s0 += e0; s1 += e1;
    }
    const float inv0 = 1.0f / s0, inv1 = 1.0f / s1;
    #pragma unroll
    for (int k = 0; k < KC; ++k) { dot0[k] *= inv0; dot1[k] *= inv1; }   // now weights

    // weights out: row stride 24 floats = 96 B, 16B-aligned per row
    #pragma unroll
    for (int q = 0; q < 6; ++q) {
        float4 w0 = make_float4(dot0[4*q], dot0[4*q+1], dot0[4*q+2], dot0[4*q+3]);
        float4 w1 = make_float4(dot1[4*q], dot1[4*q+1], dot1[4*q+2], dot1[4*q+3]);
        *(float4*)(o_w + (size_t)r0 * KC + 4 * q) = w0;
        *(float4*)(o_w + (size_t)r1 * KC + 4 * q) = w1;
    }
    o_idx[r0] = (float)idx0;
    o_idx[r1] = (float)idx1;

    // ---- Pass B: z_q_soft, z_q_hard, loss, embedding-sum bins ----
    float loss = 0.0f;
    const size_t ob0 = (size_t)r0 * DC, ob1 = (size_t)r1 * DC;
    #pragma unroll 1
    for (int c = 0; c < DC / 4; ++c) {
        const float4 a = *(const float4*)(zp0 + 4 * c);
        const float4 b = *(const float4*)(zp1 + 4 * c);
        const float4 h0 = *(const float4*)(&cb_s[idx0][4 * c]);
        const float4 h1 = *(const float4*)(&cb_s[idx1][4 * c]);
        float4 q0 = make_float4(0.f, 0.f, 0.f, 0.f);
        float4 q1 = make_float4(0.f, 0.f, 0.f, 0.f);
        #pragma unroll
        for (int k = 0; k < KC; ++k) {
            const float4 w = *(const float4*)(&cb_s[k][4 * c]);
            q0.x = fmaf(dot0[k], w.x, q0.x); q0.y = fmaf(dot0[k], w.y, q0.y);
            q0.z = fmaf(dot0[k], w.z, q0.z); q0.w = fmaf(dot0[k], w.w, q0.w);
            q1.x = fmaf(dot1[k], w.x, q1.x); q1.y = fmaf(dot1[k], w.y, q1.y);
            q1.z = fmaf(dot1[k], w.z, q1.z); q1.w = fmaf(dot1[k], w.w, q1.w);
        }
        *(float4*)(o_soft + ob0 + 4 * c) = q0;
        *(float4*)(o_soft + ob1 + 4 * c) = q1;
        *(float4*)(o_hard + ob0 + 4 * c) = h0;
        *(float4*)(o_hard + ob1 + 4 * c) = h1;
        float d;
        d = a.x - h0.x; loss = fmaf(d, d, loss);
        d = a.y - h0.y; loss = fmaf(d, d, loss);
        d = a.z - h0.z; loss = fmaf(d, d, loss);
        d = a.w - h0.w; loss = fmaf(d, d, loss);
        d = b.x - h1.x; loss = fmaf(d, d, loss);
        d = b.y - h1.y; loss = fmaf(d, d, loss);
        d = b.z - h1.z; loss = fmaf(d, d, loss);
        d = b.w - h1.w; loss = fmaf(d, d, loss);
        atomicAdd(&ebin[idx0][4 * c + 0], a.x);
        atomicAdd(&ebin[idx0][4 * c + 1], a.y);
        atomicAdd(&ebin[idx0][4 * c + 2], a.z);
        atomicAdd(&ebin[idx0][4 * c + 3], a.w);
        atomicAdd(&ebin[idx1][4 * c + 0], b.x);
        atomicAdd(&ebin[idx1][4 * c + 1], b.y);
        atomicAdd(&ebin[idx1][4 * c + 2], b.z);
        atomicAdd(&ebin[idx1][4 * c + 3], b.w);
    }
    atomicAdd(&cnt_s[idx0], 1.0f);
    atomicAdd(&cnt_s[idx1], 1.0f);

    // loss: wave reduce -> LDS -> one global atomic per block
    #pragma unroll
    for (int off = 32; off > 0; off >>= 1) loss += __shfl_down(loss, off);
    if ((tid & 63) == 0) atomicAdd(&loss_s, loss);
    __syncthreads();

    #pragma unroll 1
    for (int i = tid; i < KC * DC; i += TPB)
        atomicAdd(&acc[i], ebin[i >> 7][i & (DC - 1)]);
    if (tid < KC) atomicAdd(&acc[KC * DC + tid], cnt_s[tid]);
    if (tid == 0) atomicAdd(&acc[KC * DC + KC], loss_s);
}

__global__ void vq_epilogue(
    const float* __restrict__ z_e, const float* __restrict__ ema_cs,
    const float* __restrict__ ema_es, const int* __restrict__ rand_idx,
    const float* __restrict__ acc,
    float* __restrict__ o_loss, float* __restrict__ o_cbn,
    float* __restrict__ o_ecs, float* __restrict__ o_ees)
{
    __shared__ float ecs_s[KC], sm_s[KC];
    __shared__ float n_sh;
    const int tid = threadIdx.x;
    if (tid < KC) ecs_s[tid] = 0.95f * ema_cs[tid] + 0.05f * acc[KC * DC + tid];
    __syncthreads();
    if (tid == 0) {
        float n = 0.0f;
        for (int k = 0; k < KC; ++k) n += ecs_s[k];
        n_sh = n;
    }
    __syncthreads();
    if (tid < KC) {
        float n = n_sh;
        sm_s[tid] = (ecs_s[tid] + 1e-5f) / (n + (float)KC * 1e-5f) * n;
    }
    __syncthreads();
    #pragma unroll 1
    for (int i = tid; i < KC * DC; i += TPB) {
        int k = i >> 7, d = i & (DC - 1);
        float ees = 0.95f * ema_es[i] + 0.05f * acc[i];
        float cbn = ees / sm_s[k];
        bool dead = ecs_s[k] < 0.1f;
        float rst = z_e[(size_t)rand_idx[k] * DC + d];
        o_cbn[i] = dead ? rst : cbn;
        o_ees[i] = dead ? rst : ees;
    }
    if (tid < KC) o_ecs[tid] = (ecs_s[tid] < 0.1f) ? 1.0f : ecs_s[tid];
    if (tid == 0) o_loss[0] = 1.5f * (acc[KC * DC + KC] * (1.0f / 67108864.0f));
}

extern "C" void kernel_launch(void* const* d_in, const int* in_sizes, int n_in,
                              void* d_out, int out_size, void* d_ws, size_t ws_size,
                              hipStream_t stream) {
    const float* z_e    = (const float*)d_in[0];
    const float* cb     = (const float*)d_in[1];
    const float* ema_cs = (const float*)d_in[2];
    const float* ema_es = (const float*)d_in[3];
    const int*   ridx   = (const int*)d_in[4];

    float* out = (float*)d_out;
    float* o_soft = out;                                  // 67108864
    float* o_hard = out + 67108864ll;                     // 67108864
    float* o_idx  = out + 134217728ll;                    // 524288
    float* o_w    = out + 134742016ll;                    // 12582912
    float* o_loss = out + 147324928ll;                    // 1
    float* o_cbn  = out + 147324929ll;                    // 3072
    float* o_ecs  = out + 147328001ll;                    // 24
    float* o_ees  = out + 147328025ll;                    // 3072

    float* acc = (float*)d_ws;

    vq_zero_acc<<<(ACC_FLOATS + TPB - 1) / TPB, TPB, 0, stream>>>(acc);
    vq_main<<<NROWS / ROWS_PER_BLOCK, TPB, 0, stream>>>(
        z_e, cb, o_soft, o_hard, o_idx, o_w, acc);
    vq_epilogue<<<1, TPB, 0, stream>>>(
        z_e, ema_cs, ema_es, ridx, acc, o_loss, o_cbn, o_ecs, o_ees);
}

// Round 2
// 597.805 us; speedup vs baseline: 1.4006x; 1.4006x over previous
//
#include <hip/hip_runtime.h>

#define KC 24
#define DC 128
#define TPB 256
#define ROWS_PER_BLOCK 512
#define NROWS 524288

// workspace accumulator layout (floats):
// [0, KC*DC)          embedding sums
// [KC*DC, KC*DC+KC)   cluster counts
// [KC*DC+KC]          loss sum
#define ACC_FLOATS (KC * DC + KC + 1)

__global__ void vq_zero_acc(float* __restrict__ acc) {
    int i = blockIdx.x * blockDim.x + threadIdx.x;
    if (i < ACC_FLOATS) acc[i] = 0.0f;
}

__global__ __launch_bounds__(TPB) void vq_main(
    const float* __restrict__ z_e, const float* __restrict__ cb,
    float* __restrict__ o_soft, float* __restrict__ o_hard,
    float* __restrict__ o_idx, float* __restrict__ o_w,
    float* __restrict__ acc)
{
    __shared__ float cb_s[KC][DC + 4];
    __shared__ float wn_s[KC];
    __shared__ float ebin[KC][DC + 4];
    __shared__ float cnt_s[KC];
    __shared__ float loss_s;

    const int tid = threadIdx.x;

    #pragma unroll 1
    for (int i = tid; i < KC * DC; i += TPB) cb_s[i >> 7][i & (DC - 1)] = cb[i];
    #pragma unroll 1
    for (int i = tid; i < KC * (DC + 4); i += TPB) (&ebin[0][0])[i] = 0.0f;
    if (tid < KC) cnt_s[tid] = 0.0f;
    if (tid == 0) loss_s = 0.0f;
    __syncthreads();
    if (tid < KC) {
        float s = 0.0f;
        #pragma unroll 1
        for (int d = 0; d < DC; ++d) s = fmaf(cb_s[tid][d], cb_s[tid][d], s);
        wn_s[tid] = s;
    }
    __syncthreads();

    const int r0 = blockIdx.x * ROWS_PER_BLOCK + tid;
    const int r1 = r0 + TPB;
    const float* zp0 = z_e + (size_t)r0 * DC;
    const float* zp1 = z_e + (size_t)r1 * DC;

    float dot0[KC], dot1[KC];
    #pragma unroll
    for (int k = 0; k < KC; ++k) { dot0[k] = 0.0f; dot1[k] = 0.0f; }
    float zn0 = 0.0f, zn1 = 0.0f;

    // ---- Pass A: line-chunked (32 floats = 1 cache line per row per chunk) ----
    #pragma unroll 1
    for (int ch = 0; ch < 4; ++ch) {
        const float* pz0 = zp0 + ch * 32;
        const float* pz1 = zp1 + ch * 32;
        float4 a0[8], a1[8];
        #pragma unroll
        for (int i = 0; i < 8; ++i) a0[i] = *(const float4*)(pz0 + 4 * i);
        #pragma unroll
        for (int i = 0; i < 8; ++i) a1[i] = *(const float4*)(pz1 + 4 * i);
        #pragma unroll
        for (int i = 0; i < 8; ++i) {
            zn0 = fmaf(a0[i].x, a0[i].x, fmaf(a0[i].y, a0[i].y,
                  fmaf(a0[i].z, a0[i].z, fmaf(a0[i].w, a0[i].w, zn0))));
            zn1 = fmaf(a1[i].x, a1[i].x, fmaf(a1[i].y, a1[i].y,
                  fmaf(a1[i].z, a1[i].z, fmaf(a1[i].w, a1[i].w, zn1))));
        }
        #pragma unroll
        for (int k = 0; k < KC; ++k) {
            #pragma unroll
            for (int i = 0; i < 8; ++i) {
                const float4 w = *(const float4*)(&cb_s[k][ch * 32 + 4 * i]);
                dot0[k] = fmaf(a0[i].x, w.x, fmaf(a0[i].y, w.y,
                          fmaf(a0[i].z, w.z, fmaf(a0[i].w, w.w, dot0[k]))));
                dot1[k] = fmaf(a1[i].x, w.x, fmaf(a1[i].y, w.y,
                          fmaf(a1[i].z, w.z, fmaf(a1[i].w, w.w, dot1[k]))));
            }
        }
    }

    // ---- dists, argmin (first-min), softmax ----
    int idx0 = 0, idx1 = 0;
    float best0 = 3.4e38f, best1 = 3.4e38f;
    #pragma unroll
    for (int k = 0; k < KC; ++k) {
        const float wn = wn_s[k];
        float d0 = (zn0 - 2.0f * dot0[k]) + wn;
        float d1 = (zn1 - 2.0f * dot1[k]) + wn;
        dot0[k] = d0; dot1[k] = d1;
        if (d0 < best0) { best0 = d0; idx0 = k; }
        if (d1 < best1) { best1 = d1; idx1 = k; }
    }
    float s0 = 0.0f, s1 = 0.0f;
    #pragma unroll
    for (int k = 0; k < KC; ++k) {
        float e0 = __expf(best0 - dot0[k]);
        float e1 = __expf(best1 - dot1[k]);
        dot0[k] = e0; dot1[k] = e1;
        s0 += e0; s1 += e1;
    }
    const float inv0 = 1.0f / s0, inv1 = 1.0f / s1;
    #pragma unroll
    for (int k = 0; k < KC; ++k) { dot0[k] *= inv0; dot1[k] *= inv1; }

    // weights out (row = 96 B, lane-contiguous coverage)
    #pragma unroll
    for (int q = 0; q < 6; ++q) {
        float4 w0 = make_float4(dot0[4*q], dot0[4*q+1], dot0[4*q+2], dot0[4*q+3]);
        float4 w1 = make_float4(dot1[4*q], dot1[4*q+1], dot1[4*q+2], dot1[4*q+3]);
        *(float4*)(o_w + (size_t)r0 * KC + 4 * q) = w0;
        *(float4*)(o_w + (size_t)r1 * KC + 4 * q) = w1;
    }
    o_idx[r0] = (float)idx0;
    o_idx[r1] = (float)idx1;

    // loss: min-dist identity, Sum over rows of ||z - c_idx||^2 == best
    {
        float loss = best0 + best1;
        #pragma unroll
        for (int off = 32; off > 0; off >>= 1) loss += __shfl_down(loss, off);
        if ((tid & 63) == 0) atomicAdd(&loss_s, loss);
    }

    // ---- Pass B: line-chunked soft/hard writes + ebin accumulation ----
    const size_t ob0 = (size_t)r0 * DC, ob1 = (size_t)r1 * DC;
    #pragma unroll 1
    for (int ch = 0; ch < 4; ++ch) {
        const float* pz0 = zp0 + ch * 32;
        const float* pz1 = zp1 + ch * 32;
        float4 a0[8], a1[8];
        #pragma unroll
        for (int i = 0; i < 8; ++i) a0[i] = *(const float4*)(pz0 + 4 * i);
        #pragma unroll
        for (int i = 0; i < 8; ++i) a1[i] = *(const float4*)(pz1 + 4 * i);
        // ebin atomics (consumes a, frees regs before the k-loop)
        #pragma unroll
        for (int i = 0; i < 8; ++i) {
            const int d = ch * 32 + 4 * i;
            atomicAdd(&ebin[idx0][d + 0], a0[i].x);
            atomicAdd(&ebin[idx0][d + 1], a0[i].y);
            atomicAdd(&ebin[idx0][d + 2], a0[i].z);
            atomicAdd(&ebin[idx0][d + 3], a0[i].w);
            atomicAdd(&ebin[idx1][d + 0], a1[i].x);
            atomicAdd(&ebin[idx1][d + 1], a1[i].y);
            atomicAdd(&ebin[idx1][d + 2], a1[i].z);
            atomicAdd(&ebin[idx1][d + 3], a1[i].w);
        }
        // soft: full-line accumulate then 8 back-to-back float4 stores per row
        float4 q0[8], q1[8];
        #pragma unroll
        for (int i = 0; i < 8; ++i) {
            q0[i] = make_float4(0.f, 0.f, 0.f, 0.f);
            q1[i] = make_float4(0.f, 0.f, 0.f, 0.f);
        }
        #pragma unroll
        for (int k = 0; k < KC; ++k) {
            const float w0 = dot0[k], w1 = dot1[k];
            #pragma unroll
            for (int i = 0; i < 8; ++i) {
                const float4 w = *(const float4*)(&cb_s[k][ch * 32 + 4 * i]);
                q0[i].x = fmaf(w0, w.x, q0[i].x); q0[i].y = fmaf(w0, w.y, q0[i].y);
                q0[i].z = fmaf(w0, w.z, q0[i].z); q0[i].w = fmaf(w0, w.w, q0[i].w);
                q1[i].x = fmaf(w1, w.x, q1[i].x); q1[i].y = fmaf(w1, w.y, q1[i].y);
                q1[i].z = fmaf(w1, w.z, q1[i].z); q1[i].w = fmaf(w1, w.w, q1[i].w);
            }
        }
        #pragma unroll
        for (int i = 0; i < 8; ++i) *(float4*)(o_soft + ob0 + ch * 32 + 4 * i) = q0[i];
        #pragma unroll
        for (int i = 0; i < 8; ++i) *(float4*)(o_soft + ob1 + ch * 32 + 4 * i) = q1[i];
        // hard: full-line copies from LDS codebook
        #pragma unroll
        for (int i = 0; i < 8; ++i) {
            const float4 h = *(const float4*)(&cb_s[idx0][ch * 32 + 4 * i]);
            *(float4*)(o_hard + ob0 + ch * 32 + 4 * i) = h;
        }
        #pragma unroll
        for (int i = 0; i < 8; ++i) {
            const float4 h = *(const float4*)(&cb_s[idx1][ch * 32 + 4 * i]);
            *(float4*)(o_hard + ob1 + ch * 32 + 4 * i) = h;
        }
    }
    atomicAdd(&cnt_s[idx0], 1.0f);
    atomicAdd(&cnt_s[idx1], 1.0f);
    __syncthreads();

    #pragma unroll 1
    for (int i = tid; i < KC * DC; i += TPB)
        atomicAdd(&acc[i], ebin[i >> 7][i & (DC - 1)]);
    if (tid < KC) atomicAdd(&acc[KC * DC + tid], cnt_s[tid]);
    if (tid == 0) atomicAdd(&acc[KC * DC + KC], loss_s);
}

__global__ void vq_epilogue(
    const float* __restrict__ z_e, const float* __restrict__ ema_cs,
    const float* __restrict__ ema_es, const int* __restrict__ rand_idx,
    const float* __restrict__ acc,
    float* __restrict__ o_loss, float* __restrict__ o_cbn,
    float* __restrict__ o_ecs, float* __restrict__ o_ees)
{
    __shared__ float ecs_s[KC], sm_s[KC];
    __shared__ float n_sh;
    const int tid = threadIdx.x;
    if (tid < KC) ecs_s[tid] = 0.95f * ema_cs[tid] + 0.05f * acc[KC * DC + tid];
    __syncthreads();
    if (tid == 0) {
        float n = 0.0f;
        for (int k = 0; k < KC; ++k) n += ecs_s[k];
        n_sh = n;
    }
    __syncthreads();
    if (tid < KC) {
        float n = n_sh;
        sm_s[tid] = (ecs_s[tid] + 1e-5f) / (n + (float)KC * 1e-5f) * n;
    }
    __syncthreads();
    #pragma unroll 1
    for (int i = tid; i < KC * DC; i += TPB) {
        int k = i >> 7, d = i & (DC - 1);
        float ees = 0.95f * ema_es[i] + 0.05f * acc[i];
        float cbn = ees / sm_s[k];
        bool dead = ecs_s[k] < 0.1f;
        float rst = z_e[(size_t)rand_idx[k] * DC + d];
        o_cbn[i] = dead ? rst : cbn;
        o_ees[i] = dead ? rst : ees;
    }
    if (tid < KC) o_ecs[tid] = (ecs_s[tid] < 0.1f) ? 1.0f : ecs_s[tid];
    if (tid == 0) o_loss[0] = 1.5f * (acc[KC * DC + KC] * (1.0f / 67108864.0f));
}

extern "C" void kernel_launch(void* const* d_in, const int* in_sizes, int n_in,
                              void* d_out, int out_size, void* d_ws, size_t ws_size,
                              hipStream_t stream) {
    const float* z_e    = (const float*)d_in[0];
    const float* cb     = (const float*)d_in[1];
    const float* ema_cs = (const float*)d_in[2];
    const float* ema_es = (const float*)d_in[3];
    const int*   ridx   = (const int*)d_in[4];

    float* out = (float*)d_out;
    float* o_soft = out;                                  // 67108864
    float* o_hard = out + 67108864ll;                     // 67108864
    float* o_idx  = out + 134217728ll;                    // 524288
    float* o_w    = out + 134742016ll;                    // 12582912
    float* o_loss = out + 147324928ll;                    // 1
    float* o_cbn  = out + 147324929ll;                    // 3072
    float* o_ecs  = out + 147328001ll;                    // 24
    float* o_ees  = out + 147328025ll;                    // 3072

    float* acc = (float*)d_ws;

    vq_zero_acc<<<(ACC_FLOATS + TPB - 1) / TPB, TPB, 0, stream>>>(acc);
    vq_main<<<NROWS / ROWS_PER_BLOCK, TPB, 0, stream>>>(
        z_e, cb, o_soft, o_hard, o_idx, o_w, acc);
    vq_epilogue<<<1, TPB, 0, stream>>>(
        z_e, ema_cs, ema_es, ridx, acc, o_loss, o_cbn, o_ecs, o_ees);
}